// Round 3
// baseline (2640.376 us; speedup 1.0000x reference)
//
#include <hip/hip_runtime.h>
#include <hip/hip_fp16.h>
#include <stdint.h>

#define NSEG 10000
#define NNODES 500000

typedef unsigned short u16;
typedef _Float16 f16x8 __attribute__((ext_vector_type(8)));
typedef float f32x4 __attribute__((ext_vector_type(4)));

__device__ __forceinline__ u16 f2h(float x) {
  return __half_as_ushort(__float2half(x));
}

typedef const __attribute__((address_space(1))) void* as1_cvp;
typedef __attribute__((address_space(3))) void* as3_vp;

__device__ __forceinline__ void gload_lds16(const void* g, void* l) {
  __builtin_amdgcn_global_load_lds((as1_cvp)g, (as3_vp)l, 16, 0, 0);
}

// ---------------- prep kernels ----------------

__global__ void seg_bounds(const int* __restrict__ seg, int* __restrict__ out) {
  int t = blockIdx.x * 256 + threadIdx.x;
  if (t > NSEG) return;
  int lo = 0, hi = NNODES;
  while (lo < hi) { int mid = (lo + hi) >> 1; if (seg[mid] < t) lo = mid + 1; else hi = mid; }
  out[t] = lo;
}

// weights: wc rows of length 2K = [W_row | W_row] (duplicated along K), fp16.
// W_row = [w_ih(insz) | w_hh(256)].
__global__ void prep_weights(const float* wih0, const float* whh0, const float* bih0, const float* bhh0,
                             const float* wih1, const float* whh1, const float* bih1, const float* bhh1,
                             const float* wih2, const float* whh2, const float* bih2, const float* bhh2,
                             u16* wc0, u16* wc1, u16* wc2, float* bsum) {
  int row = blockIdx.x, l = blockIdx.y;
  const float* wih = l == 0 ? wih0 : l == 1 ? wih1 : wih2;
  const float* whh = l == 0 ? whh0 : l == 1 ? whh1 : whh2;
  int insz = l == 0 ? 512 : 256;
  int K = insz + 256;
  u16* dst = l == 0 ? wc0 : l == 1 ? wc1 : wc2;
  for (int col = threadIdx.x; col < 2 * K; col += 256) {
    int inner = col % K;
    float v = (inner < insz) ? wih[(size_t)row * insz + inner] : whh[(size_t)row * 256 + (inner - insz)];
    dst[(size_t)row * 2 * K + col] = f2h(v);
  }
  if (threadIdx.x == 0) {
    const float* bih = l == 0 ? bih0 : l == 1 ? bih1 : bih2;
    const float* bhh = l == 0 ? bhh0 : l == 1 ? bhh1 : bhh2;
    bsum[l * 1024 + row] = bih[row] + bhh[row];
  }
}

// ---------------- GEMM: C[M][1024] = A[M][KT] * B[1024][KT]^T (fp16 in, f32 out) ----------------
// 128x128 tile, BK=64, 4 waves in 2x2, 16x16x32 MFMA, global_load_lds + XOR swizzle.

template <int KT>
__global__ __launch_bounds__(256) void gemm_f16(const u16* __restrict__ A, const u16* __restrict__ B,
                                                float* __restrict__ C, int M) {
  constexpr int BK = 64;
  __shared__ u16 At[128 * 64];
  __shared__ u16 Bt[128 * 64];
  const int tid = threadIdx.x;
  const int w = tid >> 6, lane = tid & 63;
  const int wr = w >> 1, wc = w & 1;
  const int tile_m = blockIdx.y * 128;
  const int tile_n = blockIdx.x * 128;
  const int lr = lane & 15, lk = lane >> 4;

  f32x4 acc[4][4] = {};

  for (int k0 = 0; k0 < KT; k0 += BK) {
#pragma unroll
    for (int i = 0; i < 4; ++i) {
      int fbase = w * 512 + i * 2048;            // wave-uniform ushort offset
      int f = fbase + lane * 8;                   // this lane's linear ushort index
      int fs = f ^ (((f >> 6) & 7) << 3);         // swizzled source index (involution)
      int row = fs >> 6, col = fs & 63;
      int grow = tile_m + row; if (grow >= M) grow = M - 1;
      gload_lds16(A + (size_t)grow * KT + k0 + col, &At[fbase]);
      gload_lds16(B + (size_t)(tile_n + row) * KT + k0 + col, &Bt[fbase]);
    }
    __syncthreads();
#pragma unroll
    for (int kk = 0; kk < BK; kk += 32) {
      f16x8 af[4], bfr[4];
#pragma unroll
      for (int r = 0; r < 4; ++r) {
        int row = wr * 64 + r * 16 + lr;
        int idx = (row * 64 + kk + lk * 8) ^ ((row & 7) << 3);
        af[r] = *(const f16x8*)&At[idx];
      }
#pragma unroll
      for (int c = 0; c < 4; ++c) {
        int row = wc * 64 + c * 16 + lr;
        int idx = (row * 64 + kk + lk * 8) ^ ((row & 7) << 3);
        bfr[c] = *(const f16x8*)&Bt[idx];
      }
#pragma unroll
      for (int r = 0; r < 4; ++r)
#pragma unroll
        for (int c = 0; c < 4; ++c)
          acc[r][c] = __builtin_amdgcn_mfma_f32_16x16x32_f16(af[r], bfr[c], acc[r][c], 0, 0, 0);
    }
    __syncthreads();
  }

  // epilogue: C/D layout col = lane&15, row = (lane>>4)*4 + reg
#pragma unroll
  for (int r = 0; r < 4; ++r)
#pragma unroll
    for (int c = 0; c < 4; ++c)
#pragma unroll
      for (int j = 0; j < 4; ++j) {
        int row = tile_m + wr * 64 + r * 16 + lk * 4 + j;
        int col = tile_n + wc * 64 + c * 16 + lr;
        if (row < M) C[(size_t)row * 1024 + col] = acc[r][c][j];
      }
}

// ---------------- LSTM pointwise ----------------
// Writes h as fp16 hi/lo pairs into two destination activation buffers.

__global__ __launch_bounds__(256) void lstm_pw(const float* __restrict__ gates,
                                               const float* __restrict__ bsum,
                                               float* __restrict__ c,
                                               u16* __restrict__ hdst0, int stride0, int off0, int lodelta0,
                                               u16* __restrict__ hdst1, int stride1, int off1, int lodelta1,
                                               float* __restrict__ qout) {
  int b = blockIdx.x, d = threadIdx.x;
  size_t g0 = (size_t)b * 1024;
  float xi = gates[g0 + d] + bsum[d];
  float xf = gates[g0 + 256 + d] + bsum[256 + d];
  float xg = gates[g0 + 512 + d] + bsum[512 + d];
  float xo = gates[g0 + 768 + d] + bsum[768 + d];
  float i = 1.f / (1.f + expf(-xi));
  float f = 1.f / (1.f + expf(-xf));
  float g = tanhf(xg);
  float o = 1.f / (1.f + expf(-xo));
  size_t ci = (size_t)b * 256 + d;
  float cn = f * c[ci] + i * g;
  c[ci] = cn;
  float h = o * tanhf(cn);
  __half hh = __float2half(h);
  u16 hb = __half_as_ushort(hh);
  u16 lb = f2h(h - __half2float(hh));
  hdst0[(size_t)b * stride0 + off0 + d] = hb;
  hdst0[(size_t)b * stride0 + off0 + lodelta0 + d] = lb;
  hdst1[(size_t)b * stride1 + off1 + d] = hb;
  hdst1[(size_t)b * stride1 + off1 + lodelta1 + d] = lb;
  if (qout) qout[(size_t)b * 512 + d] = h;
}

// ---------------- fused attention: one block per segment, single-pass online softmax ----------------

__global__ __launch_bounds__(256) void attn_kernel(const float4* __restrict__ feats4,
                                                   const int* __restrict__ segst,
                                                   float* __restrict__ out,
                                                   u16* __restrict__ xh0) {
  int b = blockIdx.x;
  int start = segst[b], end = segst[b + 1];
  int w = threadIdx.x >> 6, lane = threadIdx.x & 63;
  __shared__ float m_s[4], s_s[4];
  __shared__ float4 acc_s[4][64];

  float4 q4 = ((const float4*)out)[(size_t)b * 128 + lane];  // q = out[b, 0:256]
  float m = -INFINITY, s = 0.f;
  float ax = 0.f, ay = 0.f, az = 0.f, aw = 0.f;

  for (int n = start + w; n < end; n += 4) {
    float4 f = feats4[(size_t)n * 64 + lane];
    float e = f.x * q4.x + f.y * q4.y + f.z * q4.z + f.w * q4.w;
#pragma unroll
    for (int off = 32; off > 0; off >>= 1) e += __shfl_xor(e, off);
    float mn = fmaxf(m, e);
    float sc = expf(m - mn);   // first iter: exp(-inf)=0
    float p = expf(e - mn);
    s = s * sc + p;
    ax = ax * sc + p * f.x; ay = ay * sc + p * f.y;
    az = az * sc + p * f.z; aw = aw * sc + p * f.w;
    m = mn;
  }
  acc_s[w][lane] = make_float4(ax, ay, az, aw);
  if (lane == 0) { m_s[w] = m; s_s[w] = s; }
  __syncthreads();

  int d = threadIdx.x;
  float res = 0.f;
  if (start < end) {
    float mm = fmaxf(fmaxf(m_s[0], m_s[1]), fmaxf(m_s[2], m_s[3]));
    float stot = 0.f, num = 0.f;
#pragma unroll
    for (int wv = 0; wv < 4; ++wv) {
      float sc = expf(m_s[wv] - mm);  // -inf -> 0
      stot += s_s[wv] * sc;
      num += ((const float*)&acc_s[wv][0])[d] * sc;
    }
    res = num / stot;
  }
  out[(size_t)b * 512 + 256 + d] = res;            // r part of q_star
  __half rh = __float2half(res);
  xh0[(size_t)b * 1536 + 256 + d] = __half_as_ushort(rh);             // r_hi
  xh0[(size_t)b * 1536 + 1024 + d] = f2h(res - __half2float(rh));     // r_lo (768+256)
}

// ---------------- orchestration ----------------
// xh0 row (1536): [q_hi(256) r_hi(256) h0_hi(256) | q_lo r_lo h0_lo]
// xh1 row (1024): [h0'_hi(256) h1_hi(256) | h0'_lo h1_lo]
// xh2 row (1024): [h1'_hi(256) h2_hi(256) | h1'_lo h2_lo]

extern "C" void kernel_launch(void* const* d_in, const int* in_sizes, int n_in,
                              void* d_out, int out_size, void* d_ws, size_t ws_size,
                              hipStream_t stream) {
  (void)in_sizes; (void)n_in; (void)out_size; (void)ws_size;
  const float* feats = (const float*)d_in[0];
  const int* segids = (const int*)d_in[1];
  float* out = (float*)d_out;

  char* p = (char*)d_ws;
  auto alloc = [&](size_t bytes) -> char* {
    char* r = p; p += (bytes + 255) & ~(size_t)255; return r;
  };
  u16* xh0 = (u16*)alloc((size_t)NSEG * 1536 * 2);
  u16* xh1 = (u16*)alloc((size_t)NSEG * 1024 * 2);
  u16* xh2 = (u16*)alloc((size_t)NSEG * 1024 * 2);
  float* cbuf = (float*)alloc((size_t)3 * NSEG * 256 * 4);
  float* gates = (float*)alloc((size_t)NSEG * 1024 * 4);
  u16* wc0 = (u16*)alloc((size_t)1024 * 1536 * 2);
  u16* wc1 = (u16*)alloc((size_t)1024 * 1024 * 2);
  u16* wc2 = (u16*)alloc((size_t)1024 * 1024 * 2);
  float* bsum = (float*)alloc(3 * 1024 * 4);
  int* segst = (int*)alloc((NSEG + 1) * 4);

  hipMemsetAsync(xh0, 0, (size_t)NSEG * 1536 * 2, stream);
  hipMemsetAsync(xh1, 0, (size_t)NSEG * 1024 * 2, stream);
  hipMemsetAsync(xh2, 0, (size_t)NSEG * 1024 * 2, stream);
  hipMemsetAsync(cbuf, 0, (size_t)3 * NSEG * 256 * 4, stream);

  prep_weights<<<dim3(1024, 3), 256, 0, stream>>>(
      (const float*)d_in[2], (const float*)d_in[3], (const float*)d_in[4], (const float*)d_in[5],
      (const float*)d_in[6], (const float*)d_in[7], (const float*)d_in[8], (const float*)d_in[9],
      (const float*)d_in[10], (const float*)d_in[11], (const float*)d_in[12], (const float*)d_in[13],
      wc0, wc1, wc2, bsum);
  seg_bounds<<<(NSEG + 256) / 256, 256, 0, stream>>>(segids, segst);

  float* c0 = cbuf;
  float* c1 = cbuf + (size_t)NSEG * 256;
  float* c2 = cbuf + (size_t)2 * NSEG * 256;

  for (int it = 0; it < 6; ++it) {
    // layer 0: x = q_star(512) ++ h0(256), K=768 -> split K'=1536
    gemm_f16<1536><<<dim3(8, 79), 256, 0, stream>>>(xh0, wc0, gates, NSEG);
    lstm_pw<<<NSEG, 256, 0, stream>>>(gates, bsum, c0,
                                      xh0, 1536, 512, 768,   // h0 state
                                      xh1, 1024, 0, 512,     // x for layer 1
                                      nullptr);
    // layer 1: x = h0'(256) ++ h1(256), K=512 -> split K'=1024
    gemm_f16<1024><<<dim3(8, 79), 256, 0, stream>>>(xh1, wc1, gates, NSEG);
    lstm_pw<<<NSEG, 256, 0, stream>>>(gates, bsum + 1024, c1,
                                      xh1, 1024, 256, 512,   // h1 state
                                      xh2, 1024, 0, 512,     // x for layer 2
                                      nullptr);
    // layer 2: x = h1'(256) ++ h2(256), K=512 -> split K'=1024
    gemm_f16<1024><<<dim3(8, 79), 256, 0, stream>>>(xh2, wc2, gates, NSEG);
    lstm_pw<<<NSEG, 256, 0, stream>>>(gates, bsum + 2048, c2,
                                      xh2, 1024, 256, 512,   // h2 state
                                      xh0, 1536, 0, 768,     // q slot
                                      out);
    // attention: q from out[:,0:256] -> r into out[:,256:512] and xh0 (hi/lo)
    attn_kernel<<<NSEG, 256, 0, stream>>>((const float4*)feats, segst, out, xh0);
  }
}